// Round 2
// 126.590 us; speedup vs baseline: 1.0931x; 1.0931x over previous
//
#include <hip/hip_runtime.h>

#define NTOK 4096
#define NBH  32
// Symmetric-compressed feature rows:
//   [0,32)    linear k_i                          (weight a1 = 1)
//   [32,512)  s-blocks s=1..15: k_i * k_{(i+s)&31} (weight 1 = 2*a2, pair once)
//   [512,528) s=16:     k_i * k_{i+16}, i<16       (weight 1)
//   [528,560) diagonal  0.5 * k_i^2                (weight a2 = 0.5)
//   560       const 1                              (a0 term)
//   [561,576) pad (zero)
#define NF   576
#define NE   33     // stored G columns: 32 v-cols + 1 ones-col (denominator)
#define NKT  18     // b-side 32-feature chunks
#define GTF_BH (NKT * 3 * 64 * 8)   // 27648 halves per bh

typedef _Float16 half_t;
typedef _Float16 half8 __attribute__((ext_vector_type(8)));
typedef _Float16 half4v __attribute__((ext_vector_type(4)));
typedef float f32x4 __attribute__((ext_vector_type(4)));
typedef unsigned int u32;

#define MFMA16(A,B,C) __builtin_amdgcn_mfma_f32_16x16x32_f16((A),(B),(C),0,0,0)

// async 16B global->LDS: lds dst = wave-uniform base + lane*16
#define ASYNC_CP16(dst_lds, src_glb) \
    __builtin_amdgcn_global_load_lds( \
        (const __attribute__((address_space(1))) u32*)(const void*)(src_glb), \
        (__attribute__((address_space(3))) u32*)(void*)(dst_lds), 16, 0, 0)

static __device__ __forceinline__ half8 splat8(half_t x) {
    return (half8){x, x, x, x, x, x, x, x};
}

// ---------------------------------------------------------------------------
// T: transpose + fp32->fp16  k,v [bh][n][32] -> [bh][32][n]   (unchanged)
// ---------------------------------------------------------------------------
__global__ __launch_bounds__(256)
void t_kernel(const float* __restrict__ kin, const float* __restrict__ vin,
              half_t* __restrict__ kTg, half_t* __restrict__ vTg)
{
    const int nb = blockIdx.x;     // 16 blocks of 256 n
    const int bh = blockIdx.y;
    const int t  = threadIdx.x;
    __shared__ __align__(16) half_t tile[32 * 272];
    const size_t inbase = ((size_t)bh * NTOK + nb * 256) * 32;

    for (int pass = 0; pass < 2; ++pass) {
        const float* src = pass ? vin : kin;
        half_t* dstg     = pass ? vTg : kTg;
        if (pass) __syncthreads();
        const float4* s4 = (const float4*)(src + inbase);
        #pragma unroll
        for (int r = 0; r < 8; ++r) {
            int f4 = t + 256 * r;
            int n = f4 >> 3, d4 = f4 & 7;
            float4 vv = s4[f4];
            int nn = n ^ ((d4 & 7) << 3);
            int d0 = d4 * 4;
            tile[(d0 + 0) * 272 + nn] = (half_t)vv.x;
            tile[(d0 + 1) * 272 + nn] = (half_t)vv.y;
            tile[(d0 + 2) * 272 + nn] = (half_t)vv.z;
            tile[(d0 + 3) * 272 + nn] = (half_t)vv.w;
        }
        __syncthreads();
        #pragma unroll
        for (int cc = 0; cc < 4; ++cc) {
            int lin = t + 256 * cc;
            int d = lin >> 5, ch = lin & 31;
            int sw = (d >> 2) & 7;
            half8 val = *(const half8*)&tile[d * 272 + ((ch ^ sw) << 3)];
            *(half8*)&dstg[((size_t)bh * 32 + d) * NTOK + nb * 256 + ch * 8] = val;
        }
    }
}

// ---------------------------------------------------------------------------
// A: G[p][e] = sum_n phi(k_n)[p] * [v_n | 1][e] via f16 MFMA, over the
// symmetric-compressed 576-row feature map. 36 tiles, 9 per wave (pw=w*144).
// s-block tiles: af = k_{i0+l16} * rotated LDS row (i0+l16+s)&31 — the
// rotated read uses the same chunk-XOR swizzle (2-way, free).
// Double-buffered global_load_lds staging, one barrier per stage.
// ---------------------------------------------------------------------------
__global__ __launch_bounds__(256, 2)
void a_kernel(const half_t* __restrict__ kTg, const half_t* __restrict__ vTg,
              half_t* __restrict__ P, int Kc)
{
    const int x  = blockIdx.x;
    const int bh = x & (NBH - 1);
    const int kc = x >> 5;
    const int t = threadIdx.x;
    const int w = t >> 6, lane = t & 63, l16 = lane & 15, quad = lane >> 4;
    const int pw = w * 144;

    __shared__ __align__(16) half_t kT0[2 * 4096];
    __shared__ __align__(16) half_t vT0[2 * 4096];

    const half8 h05 = splat8((half_t)0.5f);
    f32x4 acc[9][3];
    #pragma unroll
    for (int m = 0; m < 9; ++m)
        #pragma unroll
        for (int e = 0; e < 3; ++e)
            acc[m][e] = (f32x4){0.f, 0.f, 0.f, 0.f};

    // rotated-row metadata for s-block tiles (per-lane, hoisted out of K loop)
    int rotoff[9], rotsalt[9];
    #pragma unroll
    for (int mt = 0; mt < 9; ++mt) {
        const int pm = pw + mt * 16;
        int ro = 0, rs = 0;
        if (pm >= 32 && pm < 512) {
            const int s  = 1 + ((pm - 32) >> 5);
            const int i0 = (pm - 32) & 31;
            const int r  = (i0 + l16 + s) & 31;
            ro = r * 128;
            rs = r & 15;
        }
        rotoff[mt] = ro;
        rotsalt[mt] = rs;
    }

    const size_t gbase = (size_t)bh * 32 * NTOK;
    const int nPer = NTOK / Kc;
    const int nStages = nPer >> 7;

    // staging source map (incorporates the chunk-XOR LDS swizzle)
    const int c0 = t,        r0 = c0 >> 4, p0s = (c0 & 15) ^ (r0 & 15);
    const int c1 = 256 + t,  r1 = c1 >> 4, p1s = (c1 & 15) ^ (r1 & 15);

    auto issue = [&](int buf, int nbase) {
        const half_t* gk0 = kTg + gbase + (size_t)r0 * NTOK + nbase + p0s * 8;
        const half_t* gk1 = kTg + gbase + (size_t)r1 * NTOK + nbase + p1s * 8;
        const half_t* gv0 = vTg + gbase + (size_t)r0 * NTOK + nbase + p0s * 8;
        const half_t* gv1 = vTg + gbase + (size_t)r1 * NTOK + nbase + p1s * 8;
        half_t* kb = kT0 + buf * 4096;
        half_t* vb = vT0 + buf * 4096;
        ASYNC_CP16(kb + (size_t)w * 512,        gk0);
        ASYNC_CP16(kb + 2048 + (size_t)w * 512, gk1);
        ASYNC_CP16(vb + (size_t)w * 512,        gv0);
        ASYNC_CP16(vb + 2048 + (size_t)w * 512, gv1);
    };

    issue(0, kc * nPer);

    for (int st = 0; st < nStages; ++st) {
        const int cur = st & 1;
        __syncthreads();   // drains copy(cur); all waves done with buf cur^1
        if (st + 1 < nStages) issue(cur ^ 1, kc * nPer + (st + 1) * 128);
        const half_t* kb = kT0 + cur * 4096;
        const half_t* vb = vT0 + cur * 4096;
        #pragma unroll
        for (int kk = 0; kk < 4; ++kk) {
            const int c = kk * 4 + quad;
            const int shL = ((c ^ l16) << 3);
            half8 kj0 = *(const half8*)&kb[l16 * 128 + shL];
            half8 kj1 = *(const half8*)&kb[(l16 + 16) * 128 + shL];
            half8 bf0 = *(const half8*)&vb[l16 * 128 + shL];
            half8 bf1 = *(const half8*)&vb[(l16 + 16) * 128 + shL];
            half_t onec = (l16 == 0) ? (half_t)1 : (half_t)0;
            half8 bf2 = splat8(onec);
            #pragma unroll
            for (int mt = 0; mt < 9; ++mt) {
                const int pm = pw + mt * 16;
                half8 af;
                if (pm < 32) {
                    af = pm ? kj1 : kj0;                      // linear
                } else if (pm < 512) {
                    half8 rot = *(const half8*)&kb[rotoff[mt] + ((c ^ rotsalt[mt]) << 3)];
                    af = (((pm - 32) & 16) ? kj1 : kj0) * rot; // pair {i, i+s}
                } else if (pm == 512) {
                    af = kj0 * kj1;                           // s=16 pairs
                } else if (pm == 528) {
                    af = (kj0 * h05) * kj0;                   // diag i<16
                } else if (pm == 544) {
                    af = (kj1 * h05) * kj1;                   // diag i>=16
                } else {
                    af = bf2;                                 // const row (560)
                }
                acc[mt][0] = MFMA16(af, bf0, acc[mt][0]);
                acc[mt][1] = MFMA16(af, bf1, acc[mt][1]);
                acc[mt][2] = MFMA16(af, bf2, acc[mt][2]);
            }
        }
    }

    half_t* Pb = P + ((size_t)kc * NBH + bh) * NE * NF;
    #pragma unroll
    for (int mt = 0; mt < 9; ++mt) {
        int p0 = pw + mt * 16 + quad * 4;
        half4v h0 = {(half_t)acc[mt][0][0], (half_t)acc[mt][0][1],
                     (half_t)acc[mt][0][2], (half_t)acc[mt][0][3]};
        half4v h1 = {(half_t)acc[mt][1][0], (half_t)acc[mt][1][1],
                     (half_t)acc[mt][1][2], (half_t)acc[mt][1][3]};
        *(half4v*)&Pb[(size_t)l16 * NF + p0] = h0;
        *(half4v*)&Pb[(size_t)(l16 + 16) * NF + p0] = h1;
        if (l16 == 0) {
            half4v h2 = {(half_t)acc[mt][2][0], (half_t)acc[mt][2][1],
                         (half_t)acc[mt][2][2], (half_t)acc[mt][2][3]};
            *(half4v*)&Pb[(size_t)32 * NF + p0] = h2;
        }
    }
}

// ---------------------------------------------------------------------------
// AR: sum Kc fp16 partial planes (fp32 accum) -> GtF in MFMA-B-FRAGMENT order:
//   GtF[bh][kt(18)][rr(3)][lane=quad*16+l16][j(8)]
// ---------------------------------------------------------------------------
__global__ __launch_bounds__(256)
void ar_kernel(const half_t* __restrict__ P, half_t* __restrict__ GtF, int Kc)
{
    const int NP8 = NBH * NE * NF / 8;   // 76032
    const int idx = blockIdx.x * 256 + threadIdx.x;
    if (idx >= NP8) return;
    float s[8] = {0.f, 0.f, 0.f, 0.f, 0.f, 0.f, 0.f, 0.f};
    for (int c = 0; c < Kc; ++c) {
        half8 h = *(const half8*)&P[(size_t)c * (NBH * NE * NF) + (size_t)idx * 8];
        #pragma unroll
        for (int j = 0; j < 8; ++j) s[j] += (float)h[j];
    }
    half8 o;
    #pragma unroll
    for (int j = 0; j < 8; ++j) o[j] = (half_t)s[j];
    int row = idx / 72;                  // NF/8
    int p8 = idx - row * 72;
    int e = row % 33, bhh = row / 33;
    int kt = p8 >> 2, quad = p8 & 3;
    int rr = e >> 4, l16 = e & 15;       // e==32 -> rr=2, l16=0
    size_t dst8 = (size_t)bhh * (GTF_BH / 8)
                + (size_t)(kt * 3 + rr) * 64 + quad * 16 + l16;
    *(half8*)&GtF[dst8 * 8] = o;
}

// ---------------------------------------------------------------------------
// B: out[n][e] = (phi(q_n).G[:,e]) / (phi(q_n).G[:,32]) via f16 MFMA over
// 18 feature chunks. Rotated q-factor built in-register: preloaded aligned
// half8s vq/hv/gv + compile-time shufflevector (per-chunk shift s&7).
// qs2 rows hold dims 0..31 plus a 16-dim wraparound copy (56-half stride,
// 2-way bank pattern). Depth-3 register ring on GtF fragments.
// ---------------------------------------------------------------------------
__global__ __launch_bounds__(256)
void b_kernel(const float* __restrict__ qin, const half_t* __restrict__ GtF,
              float* __restrict__ out)
{
    const int bh = blockIdx.x, mbq = blockIdx.y;   // 32 x 16
    const int t = threadIdx.x, w = t >> 6, lane = t & 63;
    const int l16 = lane & 15, quad = lane >> 4;
    __shared__ __align__(16) half_t qs2[256 * 56];
    __shared__ float denl[256];
    const size_t nbase = (size_t)bh * NTOK + mbq * 256;

    const float4* q4 = (const float4*)(qin + nbase * 32);
    #pragma unroll
    for (int r = 0; r < 8; ++r) {
        int f4 = t + 256 * r, n = f4 >> 3, d4 = f4 & 7;
        float4 vv = q4[f4];
        half4v h = {(half_t)vv.x, (half_t)vv.y, (half_t)vv.z, (half_t)vv.w};
        *(half4v*)&qs2[n * 56 + d4 * 4] = h;
        if (d4 < 4) *(half4v*)&qs2[n * 56 + 32 + d4 * 4] = h;  // wrap copy dims 0..15
    }
    __syncthreads();

    const int rbase = w * 64;
    int tb[4];
    #pragma unroll
    for (int mt = 0; mt < 4; ++mt) tb[mt] = (rbase + mt * 16 + l16) * 56;

    half8 vq[4], hv[4], gv[4];
    #pragma unroll
    for (int mt = 0; mt < 4; ++mt) {
        const int qb = tb[mt] + quad * 8;
        vq[mt] = *(const half8*)&qs2[qb];        // dims q*8 .. +7
        hv[mt] = *(const half8*)&qs2[qb + 8];    // dims q*8+8 .. +15 (wrapped)
        gv[mt] = *(const half8*)&qs2[qb + 16];   // dims q*8+16 .. +23 (wrapped)
    }

    f32x4 acc[3][4];
    #pragma unroll
    for (int a = 0; a < 3; ++a)
        #pragma unroll
        for (int b = 0; b < 4; ++b)
            acc[a][b] = (f32x4){0.f, 0.f, 0.f, 0.f};

    const half_t* Gb = GtF + (size_t)bh * GTF_BH + (size_t)lane * 8;

#define LDF(kt, B) do { \
    _Pragma("unroll") \
    for (int rr = 0; rr < 3; ++rr) \
        (B)[rr] = *(const half8*)&Gb[(size_t)(((kt) * 3 + rr) * 64) * 8]; \
} while (0)

#define DO_MFMA(AF) do { \
    _Pragma("unroll") \
    for (int mt = 0; mt < 4; ++mt) { \
        acc[0][mt] = MFMA16((AF)[mt], B0[0], acc[0][mt]); \
        acc[1][mt] = MFMA16((AF)[mt], B0[1], acc[1][mt]); \
        acc[2][mt] = MFMA16((AF)[mt], B0[2], acc[2][mt]); \
    } \
} while (0)

#define RING() do { \
    _Pragma("unroll") \
    for (int rr = 0; rr < 3; ++rr) { B0[rr] = B1[rr]; B1[rr] = B2[rr]; B2[rr] = B3[rr]; } \
} while (0)

    half8 B0[3], B1[3], B2[3], B3[3];
    LDF(0, B0); LDF(1, B1); LDF(2, B2);

    {   // kt = 0: linear features, af = vq
        LDF(3, B3);
        DO_MFMA(vq);
        RING();
    }

    // kt = s = 1..15: af = q_i * q_{(i+s)&31} = vq * rot_s (compile-time shuffle)
#define QCHUNK(S) do { \
    if ((S) + 3 <= 17) LDF((S) + 3, B3); \
    half8 af[4]; \
    _Pragma("unroll") \
    for (int mt = 0; mt < 4; ++mt) { \
        half8 lo = ((S) < 8) ? vq[mt] : hv[mt]; \
        half8 hi = ((S) < 8) ? hv[mt] : gv[mt]; \
        half8 rot = __builtin_shufflevector(lo, hi, \
            ((S) & 7) + 0, ((S) & 7) + 1, ((S) & 7) + 2, ((S) & 7) + 3, \
            ((S) & 7) + 4, ((S) & 7) + 5, ((S) & 7) + 6, ((S) & 7) + 7); \
        af[mt] = vq[mt] * rot; \
    } \
    DO_MFMA(af); \
    RING(); \
} while (0)

    QCHUNK(1);  QCHUNK(2);  QCHUNK(3);  QCHUNK(4);  QCHUNK(5);
    QCHUNK(6);  QCHUNK(7);  QCHUNK(8);  QCHUNK(9);  QCHUNK(10);
    QCHUNK(11); QCHUNK(12); QCHUNK(13); QCHUNK(14); QCHUNK(15);

    {   // kt = 16: quads 0,1: s16 pairs q_i*q_{i+16}; quads 2,3: diag blocks 0,1
        half8 af[4];
        #pragma unroll
        for (int mt = 0; mt < 4; ++mt) {
            const int off = tb[mt] + ((quad >= 2) ? (quad - 2) : quad) * 8;
            half8 Ld = *(const half8*)&qs2[off];
            af[mt] = (quad < 2) ? (vq[mt] * gv[mt]) : (Ld * Ld);
        }
        DO_MFMA(af);
        RING();
    }
    {   // kt = 17: quads 0,1: diag blocks 2,3 (= gv^2); quad 2: const e0; quad 3: pad
        const half8 zero = {};
        half8 c10 = {};
        c10[0] = (half_t)1;
        half8 af[4];
        #pragma unroll
        for (int mt = 0; mt < 4; ++mt) {
            half8 d = gv[mt] * gv[mt];
            af[mt] = (quad < 2) ? d : ((quad == 2) ? c10 : zero);
        }
        DO_MFMA(af);
    }
#undef QCHUNK
#undef RING
#undef DO_MFMA
#undef LDF

    // broadcast den (col 32 lives in l16==0 lanes of acc[2]) via LDS
    if (l16 == 0) {
        #pragma unroll
        for (int mt = 0; mt < 4; ++mt)
            #pragma unroll
            for (int r = 0; r < 4; ++r)
                denl[rbase + mt * 16 + quad * 4 + r] = acc[2][mt][r];
    }
    __syncthreads();
    #pragma unroll
    for (int mt = 0; mt < 4; ++mt) {
        float inv[4];
        #pragma unroll
        for (int r = 0; r < 4; ++r)
            inv[r] = __builtin_amdgcn_rcpf(denl[rbase + mt * 16 + quad * 4 + r]);
        #pragma unroll
        for (int r = 0; r < 4; ++r) {
            size_t ro = (nbase + rbase + mt * 16 + quad * 4 + r) * 32;
            out[ro + l16] = acc[0][mt][r] * inv[r];
            out[ro + l16 + 16] = acc[1][mt][r] * inv[r];
        }
    }
}

// ---------------------------------------------------------------------------
extern "C" void kernel_launch(void* const* d_in, const int* in_sizes, int n_in,
                              void* d_out, int out_size, void* d_ws, size_t ws_size,
                              hipStream_t stream)
{
    const float* q = (const float*)d_in[0];
    const float* k = (const float*)d_in[1];
    const float* v = (const float*)d_in[2];
    float* out = (float*)d_out;

    const size_t planeBytes = (size_t)NBH * NE * NF * 2;   // fp16: 1,216,512
    const size_t ktBytes = (size_t)NBH * 32 * NTOK * 2;    // 8,388,608
    const size_t gtBytes = (size_t)NBH * GTF_BH * 2;       // 1,769,472
    int Kc = 16;
    while (Kc > 1 && ((size_t)Kc * planeBytes + 2 * ktBytes + gtBytes) > ws_size)
        Kc >>= 1;

    half_t* P = (half_t*)d_ws;
    half_t* kTg = (half_t*)((char*)d_ws + (size_t)Kc * planeBytes);
    half_t* vTg = kTg + (size_t)NBH * 32 * NTOK;
    half_t* GtF = vTg + (size_t)NBH * 32 * NTOK;

    t_kernel<<<dim3(16, NBH), 256, 0, stream>>>(k, v, kTg, vTg);
    a_kernel<<<dim3(Kc * NBH), 256, 0, stream>>>(kTg, vTg, P, Kc);
    const int NP8 = NBH * NE * NF / 8;   // 76032
    ar_kernel<<<(NP8 + 255) / 256, 256, 0, stream>>>(P, GtF, Kc);
    b_kernel<<<dim3(NBH, 16), 256, 0, stream>>>(q, GtF, out);
}

// Round 7
// 123.079 us; speedup vs baseline: 1.1243x; 1.0285x over previous
//
#include <hip/hip_runtime.h>

#define NTOK 4096
#define NBH  32
// Symmetric-compressed feature rows:
//   [0,32)    linear k_i                          (weight a1 = 1)
//   [32,512)  s-blocks s=1..15: k_i * k_{(i+s)&31} (weight 1 = 2*a2, pair once)
//   [512,528) s=16:     k_i * k_{i+16}, i<16       (weight 1)
//   [528,560) diagonal  0.5 * k_i^2                (weight a2 = 0.5)
//   560       const 1                              (a0 term)
//   [561,576) pad (zero)
#define NF   576
#define NE   33
#define NKT  18
#define GTF_BH (NKT * 3 * 64 * 8)   // 27648 halves per bh
#define KC   16
#define NSTG 2                       // (NTOK/KC)/128
#define NVB  (KC * NBH)              // 512 blocks
#define NP8  (NBH * NE * NF / 8)     // 76032

typedef _Float16 half_t;
typedef _Float16 half8 __attribute__((ext_vector_type(8)));
typedef _Float16 half4v __attribute__((ext_vector_type(4)));
typedef float f32x4 __attribute__((ext_vector_type(4)));

#define MFMA16(A,B,C) __builtin_amdgcn_mfma_f32_16x16x32_f16((A),(B),(C),0,0,0)

static __device__ __forceinline__ half8 splat8(half_t x) {
    return (half8){x, x, x, x, x, x, x, x};
}

// LDS group-swizzle: spreads same-(l>>4) dims across all 8 bank groups so the
// transpose's ds_write_b16 pattern is conflict-free; read-side stays 2-way.
static __device__ __forceinline__ int FS(int d) { return (d + (d >> 3)) & 15; }

// ---------------------------------------------------------------------------
// TA: fused transpose + G-build. Block (kc,bh) reads its OWN 256-token fp32
// k/v slice, converts+transposes into swizzled LDS (reg-staged, T14 split:
// next-stage loads issued before current-stage MFMAs), runs the 36-tile
// symmetric-compressed feature MFMA loop, writes one fp16 P plane.
// ---------------------------------------------------------------------------
__global__ __launch_bounds__(256, 2)
void ta_kernel(const float* __restrict__ kin, const float* __restrict__ vin,
               half_t* __restrict__ P)
{
    __shared__ __align__(16) half_t kb0[2 * 4096];
    __shared__ __align__(16) half_t vb0[2 * 4096];

    const int vb = blockIdx.x;
    const int bh = vb & (NBH - 1), kc = vb >> 5;
    const int t = threadIdx.x;
    const int w = t >> 6, lane = t & 63, l16 = lane & 15, quad = lane >> 4;
    const int pw = w * 144;
    const half8 h05 = splat8((half_t)0.5f);

    f32x4 acc[9][3];
    #pragma unroll
    for (int m = 0; m < 9; ++m)
        #pragma unroll
        for (int e = 0; e < 3; ++e)
            acc[m][e] = (f32x4){0.f, 0.f, 0.f, 0.f};

    // rotated-row metadata for s-block tiles
    int rotoff[9], rotsalt[9];
    #pragma unroll
    for (int mt = 0; mt < 9; ++mt) {
        const int pm = pw + mt * 16;
        int ro = 0, rs = 0;
        if (pm >= 32 && pm < 512) {
            const int s  = 1 + ((pm - 32) >> 5);
            const int i0 = (pm - 32) & 31;
            const int r  = (i0 + l16 + s) & 31;
            ro = r * 128;
            rs = FS(r);
        }
        rotoff[mt] = ro;
        rotsalt[mt] = rs;
    }
    const int sh0 = FS(l16), sh1 = FS(l16 + 16);

    const size_t fbase = ((size_t)bh * NTOK + kc * 256) * 32;  // float index
    const float4* k4 = (const float4*)kin + fbase / 4;
    const float4* v4 = (const float4*)vin + fbase / 4;

    float kaf[16], vaf[16];
    auto loadst = [&](int s) {
        const int base = s * 1024;   // 128 tokens * 8 float4/token
        #pragma unroll
        for (int r = 0; r < 4; ++r) {
            float4 kk = k4[base + t + 256 * r];
            float4 vv = v4[base + t + 256 * r];
            kaf[4*r+0] = kk.x; kaf[4*r+1] = kk.y; kaf[4*r+2] = kk.z; kaf[4*r+3] = kk.w;
            vaf[4*r+0] = vv.x; vaf[4*r+1] = vv.y; vaf[4*r+2] = vv.z; vaf[4*r+3] = vv.w;
        }
    };
    auto writest = [&](int buf) {
        half_t* kb = kb0 + buf * 4096;
        half_t* vb2 = vb0 + buf * 4096;
        #pragma unroll
        for (int r = 0; r < 4; ++r) {
            const int fi = t + 256 * r;
            const int n = fi >> 3, d4 = fi & 7;
            const int c = n >> 3, j = n & 7;
            #pragma unroll
            for (int i = 0; i < 4; ++i) {
                const int d = 4 * d4 + i;
                const int a = d * 128 + ((c ^ FS(d)) << 3) + j;
                kb[a] = (half_t)kaf[4*r+i];
                vb2[a] = (half_t)vaf[4*r+i];
            }
        }
    };
    auto compute = [&](int buf) {
        const half_t* kb = kb0 + buf * 4096;
        const half_t* vbp = vb0 + buf * 4096;
        #pragma unroll
        for (int kk = 0; kk < 4; ++kk) {
            const int c = kk * 4 + quad;
            half8 kj0 = *(const half8*)&kb[l16 * 128 + ((c ^ sh0) << 3)];
            half8 kj1 = *(const half8*)&kb[(l16 + 16) * 128 + ((c ^ sh1) << 3)];
            half8 bf0 = *(const half8*)&vbp[l16 * 128 + ((c ^ sh0) << 3)];
            half8 bf1 = *(const half8*)&vbp[(l16 + 16) * 128 + ((c ^ sh1) << 3)];
            half_t onec = (l16 == 0) ? (half_t)1 : (half_t)0;
            half8 bf2 = splat8(onec);
            #pragma unroll
            for (int mt = 0; mt < 9; ++mt) {
                const int pm = pw + mt * 16;
                half8 af;
                if (pm < 32) {
                    af = pm ? kj1 : kj0;                       // linear
                } else if (pm < 512) {
                    half8 rot = *(const half8*)&kb[rotoff[mt] + ((c ^ rotsalt[mt]) << 3)];
                    af = (((pm - 32) & 16) ? kj1 : kj0) * rot; // pair {i, i+s}
                } else if (pm == 512) {
                    af = kj0 * kj1;                            // s=16 pairs
                } else if (pm == 528) {
                    af = (kj0 * h05) * kj0;                    // diag i<16
                } else if (pm == 544) {
                    af = (kj1 * h05) * kj1;                    // diag i>=16
                } else {
                    af = bf2;                                  // const row (560)
                }
                acc[mt][0] = MFMA16(af, bf0, acc[mt][0]);
                acc[mt][1] = MFMA16(af, bf1, acc[mt][1]);
                acc[mt][2] = MFMA16(af, bf2, acc[mt][2]);
            }
        }
    };

    loadst(0);
    writest(0);
    __syncthreads();
    for (int st = 0; st < NSTG; ++st) {
        const int cur = st & 1;
        if (st + 1 < NSTG) loadst(st + 1);     // issue early: hides under MFMAs
        compute(cur);
        if (st + 1 < NSTG) { writest(cur ^ 1); __syncthreads(); }
    }

    half_t* Pb = P + ((size_t)kc * NBH + bh) * NE * NF;
    #pragma unroll
    for (int mt = 0; mt < 9; ++mt) {
        int p0 = pw + mt * 16 + quad * 4;
        half4v h0 = {(half_t)acc[mt][0][0], (half_t)acc[mt][0][1],
                     (half_t)acc[mt][0][2], (half_t)acc[mt][0][3]};
        half4v h1 = {(half_t)acc[mt][1][0], (half_t)acc[mt][1][1],
                     (half_t)acc[mt][1][2], (half_t)acc[mt][1][3]};
        *(half4v*)&Pb[(size_t)l16 * NF + p0] = h0;
        *(half4v*)&Pb[(size_t)(l16 + 16) * NF + p0] = h1;
        if (l16 == 0) {
            half4v h2 = {(half_t)acc[mt][2][0], (half_t)acc[mt][2][1],
                         (half_t)acc[mt][2][2], (half_t)acc[mt][2][3]};
            *(half4v*)&Pb[(size_t)32 * NF + p0] = h2;
        }
    }
}

// ---------------------------------------------------------------------------
// AR: reduce KC fp16 partial planes (fp32 accum) -> GtF fragment order:
//   GtF[bh][kt(18)][rr(3)][lane=quad*16+l16][j(8)]
// ---------------------------------------------------------------------------
__global__ __launch_bounds__(256)
void ar_kernel(const half_t* __restrict__ P, half_t* __restrict__ GtF)
{
    const int idx = blockIdx.x * 256 + threadIdx.x;
    if (idx >= NP8) return;
    float s[8] = {0.f, 0.f, 0.f, 0.f, 0.f, 0.f, 0.f, 0.f};
    for (int c = 0; c < KC; ++c) {
        half8 h = *(const half8*)&P[(size_t)c * (NBH * NE * NF) + (size_t)idx * 8];
        #pragma unroll
        for (int j = 0; j < 8; ++j) s[j] += (float)h[j];
    }
    half8 o;
    #pragma unroll
    for (int j = 0; j < 8; ++j) o[j] = (half_t)s[j];
    int row = idx / 72;                  // NF/8
    int p8 = idx - row * 72;
    int e = row % 33, bhh = row / 33;
    int kt = p8 >> 2, quad = p8 & 3;
    int rr = e >> 4, l16 = e & 15;       // e==32 -> rr=2, l16=0
    size_t dst8 = (size_t)bhh * (GTF_BH / 8)
                + (size_t)(kt * 3 + rr) * 64 + quad * 16 + l16;
    *(half8*)&GtF[dst8 * 8] = o;
}

// ---------------------------------------------------------------------------
// B: out[n][e] = (phi(q_n).G[:,e]) / (phi(q_n).G[:,32]) via f16 MFMA over
// 18 feature chunks. Rotated q-factor built in-register: preloaded aligned
// half8s vq/hv/gv + compile-time shufflevector (per-chunk shift s&7).
// qs2 rows hold dims 0..31 plus a 16-dim wraparound copy (56-half stride,
// 2-way bank pattern). Depth-3 register ring on GtF fragments.
// ---------------------------------------------------------------------------
__global__ __launch_bounds__(256)
void b_kernel(const float* __restrict__ qin, const half_t* __restrict__ GtF,
              float* __restrict__ out)
{
    const int bh = blockIdx.x, mbq = blockIdx.y;   // 32 x 16
    const int t = threadIdx.x, w = t >> 6, lane = t & 63;
    const int l16 = lane & 15, quad = lane >> 4;
    __shared__ __align__(16) half_t qs2[256 * 56];
    __shared__ float denl[256];
    const size_t nbase = (size_t)bh * NTOK + mbq * 256;

    const float4* q4 = (const float4*)(qin + nbase * 32);
    #pragma unroll
    for (int r = 0; r < 8; ++r) {
        int f4 = t + 256 * r, n = f4 >> 3, d4 = f4 & 7;
        float4 vv = q4[f4];
        half4v h = {(half_t)vv.x, (half_t)vv.y, (half_t)vv.z, (half_t)vv.w};
        *(half4v*)&qs2[n * 56 + d4 * 4] = h;
        if (d4 < 4) *(half4v*)&qs2[n * 56 + 32 + d4 * 4] = h;  // wrap dims 0..15
    }
    __syncthreads();

    const int rbase = w * 64;
    int tb[4];
    #pragma unroll
    for (int mt = 0; mt < 4; ++mt) tb[mt] = (rbase + mt * 16 + l16) * 56;

    half8 vq[4], hv[4], gv[4];
    #pragma unroll
    for (int mt = 0; mt < 4; ++mt) {
        const int qb = tb[mt] + quad * 8;
        vq[mt] = *(const half8*)&qs2[qb];
        hv[mt] = *(const half8*)&qs2[qb + 8];
        gv[mt] = *(const half8*)&qs2[qb + 16];
    }

    f32x4 acc[3][4];
    #pragma unroll
    for (int a = 0; a < 3; ++a)
        #pragma unroll
        for (int b = 0; b < 4; ++b)
            acc[a][b] = (f32x4){0.f, 0.f, 0.f, 0.f};

    const half_t* Gb = GtF + (size_t)bh * GTF_BH + (size_t)lane * 8;

#define LDF(kt, B) do { \
    _Pragma("unroll") \
    for (int rr = 0; rr < 3; ++rr) \
        (B)[rr] = *(const half8*)&Gb[(size_t)(((kt) * 3 + rr) * 64) * 8]; \
} while (0)

#define DO_MFMA(AF) do { \
    _Pragma("unroll") \
    for (int mt = 0; mt < 4; ++mt) { \
        acc[0][mt] = MFMA16((AF)[mt], B0[0], acc[0][mt]); \
        acc[1][mt] = MFMA16((AF)[mt], B0[1], acc[1][mt]); \
        acc[2][mt] = MFMA16((AF)[mt], B0[2], acc[2][mt]); \
    } \
} while (0)

#define RING() do { \
    _Pragma("unroll") \
    for (int rr = 0; rr < 3; ++rr) { B0[rr] = B1[rr]; B1[rr] = B2[rr]; B2[rr] = B3[rr]; } \
} while (0)

    half8 B0[3], B1[3], B2[3], B3[3];
    LDF(0, B0); LDF(1, B1); LDF(2, B2);

    {   // kt = 0: linear features
        LDF(3, B3);
        DO_MFMA(vq);
        RING();
    }

#define QCHUNK(S) do { \
    if ((S) + 3 <= 17) LDF((S) + 3, B3); \
    half8 af[4]; \
    _Pragma("unroll") \
    for (int mt = 0; mt < 4; ++mt) { \
        half8 lo = ((S) < 8) ? vq[mt] : hv[mt]; \
        half8 hi = ((S) < 8) ? hv[mt] : gv[mt]; \
        half8 rot = __builtin_shufflevector(lo, hi, \
            ((S) & 7) + 0, ((S) & 7) + 1, ((S) & 7) + 2, ((S) & 7) + 3, \
            ((S) & 7) + 4, ((S) & 7) + 5, ((S) & 7) + 6, ((S) & 7) + 7); \
        af[mt] = vq[mt] * rot; \
    } \
    DO_MFMA(af); \
    RING(); \
} while (0)

    QCHUNK(1);  QCHUNK(2);  QCHUNK(3);  QCHUNK(4);  QCHUNK(5);
    QCHUNK(6);  QCHUNK(7);  QCHUNK(8);  QCHUNK(9);  QCHUNK(10);
    QCHUNK(11); QCHUNK(12); QCHUNK(13); QCHUNK(14); QCHUNK(15);

    {   // kt = 16: quads 0,1: s16 pairs; quads 2,3: diag blocks 0,1
        half8 af[4];
        #pragma unroll
        for (int mt = 0; mt < 4; ++mt) {
            const int off = tb[mt] + ((quad >= 2) ? (quad - 2) : quad) * 8;
            half8 Ld = *(const half8*)&qs2[off];
            af[mt] = (quad < 2) ? (vq[mt] * gv[mt]) : (Ld * Ld);
        }
        DO_MFMA(af);
        RING();
    }
    {   // kt = 17: quads 0,1: diag blocks 2,3; quad 2: const e0; quad 3: pad
        const half8 zero = {};
        half8 c10 = {};
        c10[0] = (half_t)1;
        half8 af[4];
        #pragma unroll
        for (int mt = 0; mt < 4; ++mt) {
            half8 d = gv[mt] * gv[mt];
            af[mt] = (quad < 2) ? d : ((quad == 2) ? c10 : zero);
        }
        DO_MFMA(af);
    }
#undef QCHUNK
#undef RING
#undef DO_MFMA
#undef LDF

    if (l16 == 0) {
        #pragma unroll
        for (int mt = 0; mt < 4; ++mt)
            #pragma unroll
            for (int r = 0; r < 4; ++r)
                denl[rbase + mt * 16 + quad * 4 + r] = acc[2][mt][r];
    }
    __syncthreads();
    #pragma unroll
    for (int mt = 0; mt < 4; ++mt) {
        float inv[4];
        #pragma unroll
        for (int r = 0; r < 4; ++r)
            inv[r] = __builtin_amdgcn_rcpf(denl[rbase + mt * 16 + quad * 4 + r]);
        #pragma unroll
        for (int r = 0; r < 4; ++r) {
            size_t ro = (nbase + rbase + mt * 16 + quad * 4 + r) * 32;
            out[ro + l16] = acc[0][mt][r] * inv[r];
            out[ro + l16 + 16] = acc[1][mt][r] * inv[r];
        }
    }
}

// ---------------------------------------------------------------------------
extern "C" void kernel_launch(void* const* d_in, const int* in_sizes, int n_in,
                              void* d_out, int out_size, void* d_ws, size_t ws_size,
                              hipStream_t stream)
{
    const float* q = (const float*)d_in[0];
    const float* k = (const float*)d_in[1];
    const float* v = (const float*)d_in[2];
    float* out = (float*)d_out;

    const size_t planeHalves = (size_t)NBH * NE * NF;      // 608256
    half_t* P = (half_t*)d_ws;                             // 16 planes: 19.5 MB
    half_t* GtF = P + (size_t)KC * planeHalves;            // 1.77 MB

    ta_kernel<<<dim3(NVB), 256, 0, stream>>>(k, v, P);
    ar_kernel<<<dim3((NP8 + 255) / 256), 256, 0, stream>>>(P, GtF);
    b_kernel<<<dim3(NBH, 16), 256, 0, stream>>>(q, GtF, out);
}